// Round 5
// baseline (2825.775 us; speedup 1.0000x reference)
//
#include <hip/hip_runtime.h>
#include <hip/hip_fp16.h>
#include <cmath>

#define LVL   16
#define TSIZE (1u << 19)
#define TMASK (TSIZE - 1u)
#define HID   32
#define PRIME1 2654435761u
#define PRIME2 805459861u
#define NGROUP 8

struct Scales { float s[LVL]; };

__device__ __forceinline__ float elu_f(float v) {
    return v > 0.0f ? v : expm1f(v);
}

__device__ __forceinline__ float2 enc_level_f32(float xn0, float xn1, float xn2, float s,
                                                const float2* __restrict__ tb)
{
    float px = xn0 * s, py = xn1 * s, pz = xn2 * s;
    float fx = floorf(px), fy = floorf(py), fz = floorf(pz);
    float wx = px - fx, wy = py - fy, wz = pz - fz;
    unsigned x0 = (unsigned)fx, y0 = (unsigned)fy, z0 = (unsigned)fz;

    unsigned hy0 = y0 * PRIME1, hy1 = hy0 + PRIME1;
    unsigned hz0 = z0 * PRIME2, hz1 = hz0 + PRIME2;
    unsigned b00 = hy0 ^ hz0, b10 = hy1 ^ hz0, b01 = hy0 ^ hz1, b11 = hy1 ^ hz1;

    float2 g000 = tb[( x0       ^ b00) & TMASK];
    float2 g100 = tb[((x0 + 1u) ^ b00) & TMASK];
    float2 g010 = tb[( x0       ^ b10) & TMASK];
    float2 g110 = tb[((x0 + 1u) ^ b10) & TMASK];
    float2 g001 = tb[( x0       ^ b01) & TMASK];
    float2 g101 = tb[((x0 + 1u) ^ b01) & TMASK];
    float2 g011 = tb[( x0       ^ b11) & TMASK];
    float2 g111 = tb[((x0 + 1u) ^ b11) & TMASK];

    float ux = 1.0f - wx, uy = 1.0f - wy, uz = 1.0f - wz;
    float c00 = uy*uz, c10 = wy*uz, c01 = uy*wz, c11 = wy*wz;

    float f0 = ux * (c00*g000.x + c10*g010.x + c01*g001.x + c11*g011.x)
             + wx * (c00*g100.x + c10*g110.x + c01*g101.x + c11*g111.x);
    float f1 = ux * (c00*g000.y + c10*g010.y + c01*g001.y + c11*g011.y)
             + wx * (c00*g100.y + c10*g110.y + c01*g101.y + c11*g111.y);
    return make_float2(f0, f1);
}

// ---- XCD-sharded hash encode (fp32 table from d_in). group g = blockIdx%8
// rides the round-robin block->XCD mapping; computes levels {g, g+8} so each
// XCD's 4MB L2 only sees ~4-8MB of table.
__global__ __launch_bounds__(256, 8)
void hash_kernel(const float* __restrict__ x, const float2* __restrict__ table,
                 ushort4* __restrict__ feats, int n, Scales sc)
{
    int g = blockIdx.x & (NGROUP - 1);
    int p = (blockIdx.x >> 3) * blockDim.x + threadIdx.x;
    if (p >= n) return;

    float xn0 = (x[3*p+0] + 1.0f) * 0.5f;
    float xn1 = (x[3*p+1] + 1.0f) * 0.5f;
    float xn2 = (x[3*p+2] + 1.0f) * 0.5f;

    int l0 = g, l1 = g + NGROUP;
    float2 fa = enc_level_f32(xn0, xn1, xn2, sc.s[l0], table + (size_t)l0 * TSIZE);
    float2 fb = enc_level_f32(xn0, xn1, xn2, sc.s[l1], table + (size_t)l1 * TSIZE);

    ushort4 pk;
    pk.x = __half_as_ushort(__float2half_rn(fa.x));
    pk.y = __half_as_ushort(__float2half_rn(fa.y));
    pk.z = __half_as_ushort(__float2half_rn(fb.x));
    pk.w = __half_as_ushort(__float2half_rn(fb.y));
    feats[(size_t)g * n + p] = pk;
}

// ---- MLP: fp32 math, weights wave-uniform (s_load), feats fp16 coalesced.
// __launch_bounds__(256, 4): min 4 waves/EU -> VGPR cap ~128, enough to keep
// two 32-float arrays in registers. Round-4 pathology: default occupancy
// target capped VGPR at 40 -> all arrays spilled -> 30x VALU inflation.
__global__ __launch_bounds__(256, 4)
void mlp_kernel(const float* __restrict__ x, const ushort4* __restrict__ feats,
                const float* __restrict__ W0, const float* __restrict__ b0,
                const float* __restrict__ W1, const float* __restrict__ b1,
                const float* __restrict__ Wout, const float* __restrict__ bout,
                float* __restrict__ out, int n)
{
    int p = blockIdx.x * blockDim.x + threadIdx.x;
    if (p >= n) return;

    float xn0 = (x[3*p+0] + 1.0f) * 0.5f;
    float xn1 = (x[3*p+1] + 1.0f) * 0.5f;
    float xn2 = (x[3*p+2] + 1.0f) * 0.5f;

    float acc[HID];
#pragma unroll
    for (int j = 0; j < HID; ++j)
        acc[j] = b0[j] + xn0 * W0[0*HID + j] + xn1 * W0[1*HID + j] + xn2 * W0[2*HID + j];

#pragma unroll
    for (int g = 0; g < NGROUP; ++g) {
        ushort4 pk = feats[(size_t)g * n + p];
        float fA = __half2float(__ushort_as_half(pk.x));
        float fB = __half2float(__ushort_as_half(pk.y));
        float fC = __half2float(__ushort_as_half(pk.z));
        float fD = __half2float(__ushort_as_half(pk.w));
        const float* rA = W0 + (3 + 2*g) * HID;
        const float* rB = W0 + (4 + 2*g) * HID;
        const float* rC = W0 + (19 + 2*g) * HID;
        const float* rD = W0 + (20 + 2*g) * HID;
#pragma unroll
        for (int j = 0; j < HID; ++j)
            acc[j] += fA * rA[j] + fB * rB[j] + fC * rC[j] + fD * rD[j];
    }

    // ELU in place: acc becomes h1 (only ONE extra 32-array needed below)
#pragma unroll
    for (int j = 0; j < HID; ++j) acc[j] = elu_f(acc[j]);

    float acc2[HID];
#pragma unroll
    for (int j = 0; j < HID; ++j) acc2[j] = b1[j];
#pragma unroll
    for (int k = 0; k < HID; ++k) {
        float hk = acc[k];
        const float* w1r = W1 + k * HID;
#pragma unroll
        for (int j = 0; j < HID; ++j) acc2[j] += hk * w1r[j];
    }

    float o = bout[0];
#pragma unroll
    for (int k = 0; k < HID; ++k) o += elu_f(acc2[k]) * Wout[k];

    out[p] = o;
}

// ---- fallback: fused fp32, with the same register-budget fix ----
__global__ __launch_bounds__(256, 4)
void fused_fp32_kernel(const float* __restrict__ x, const float* __restrict__ table,
                       const float* __restrict__ W0, const float* __restrict__ b0,
                       const float* __restrict__ W1, const float* __restrict__ b1,
                       const float* __restrict__ Wout, const float* __restrict__ bout,
                       float* __restrict__ out, int n, Scales sc)
{
    int tid = blockIdx.x * blockDim.x + threadIdx.x;
    if (tid >= n) return;

    float xn0 = (x[3*tid+0] + 1.0f) * 0.5f;
    float xn1 = (x[3*tid+1] + 1.0f) * 0.5f;
    float xn2 = (x[3*tid+2] + 1.0f) * 0.5f;

    float acc[HID];
#pragma unroll
    for (int j = 0; j < HID; ++j)
        acc[j] = b0[j] + xn0 * W0[0*HID + j] + xn1 * W0[1*HID + j] + xn2 * W0[2*HID + j];

#pragma unroll
    for (int l = 0; l < LVL; ++l) {
        const float2* tb = (const float2*)table + (size_t)l * TSIZE;
        float2 f = enc_level_f32(xn0, xn1, xn2, sc.s[l], tb);
        const float* w0r0 = W0 + (3 + 2*l) * HID;
        const float* w0r1 = W0 + (4 + 2*l) * HID;
#pragma unroll
        for (int j = 0; j < HID; ++j)
            acc[j] += f.x * w0r0[j] + f.y * w0r1[j];
    }

#pragma unroll
    for (int j = 0; j < HID; ++j) acc[j] = elu_f(acc[j]);

    float acc2[HID];
#pragma unroll
    for (int j = 0; j < HID; ++j) acc2[j] = b1[j];
#pragma unroll
    for (int k = 0; k < HID; ++k) {
        float hk = acc[k];
        const float* w1r = W1 + k * HID;
#pragma unroll
        for (int j = 0; j < HID; ++j) acc2[j] += hk * w1r[j];
    }

    float o = bout[0];
#pragma unroll
    for (int k = 0; k < HID; ++k) o += elu_f(acc2[k]) * Wout[k];

    out[tid] = o;
}

extern "C" void kernel_launch(void* const* d_in, const int* in_sizes, int n_in,
                              void* d_out, int out_size, void* d_ws, size_t ws_size,
                              hipStream_t stream)
{
    const float* x    = (const float*)d_in[0];
    const float* tb   = (const float*)d_in[1];
    const float* W0   = (const float*)d_in[2];
    const float* b0   = (const float*)d_in[3];
    const float* W1   = (const float*)d_in[4];
    const float* b1   = (const float*)d_in[5];
    const float* Wout = (const float*)d_in[6];
    const float* bo   = (const float*)d_in[7];
    float* out = (float*)d_out;

    int n = in_sizes[0] / 3;

    Scales sc;
    double B = exp(log(32.0) / 15.0);
    for (int l = 0; l < LVL; ++l)
        sc.s[l] = (float)(16.0 * pow(B, (double)l) - 1.0);

    const size_t feat_bytes = (size_t)n * NGROUP * sizeof(ushort4); // 128 MB @ n=2M
    int block = 256;
    int pgrid = (n + block - 1) / block;

    if (ws_size >= feat_bytes) {
        ushort4* feats = (ushort4*)d_ws;
        hash_kernel<<<pgrid * NGROUP, block, 0, stream>>>(x, (const float2*)tb, feats, n, sc);
        mlp_kernel<<<pgrid, block, 0, stream>>>(x, feats, W0, b0, W1, b1, Wout, bo, out, n);
    } else {
        fused_fp32_kernel<<<pgrid, block, 0, stream>>>(x, tb, W0, b0, W1, b1, Wout, bo, out, n, sc);
    }
}

// Round 6
// 1065.729 us; speedup vs baseline: 2.6515x; 2.6515x over previous
//
#include <hip/hip_runtime.h>
#include <hip/hip_fp16.h>
#include <cmath>

#define LVL   16
#define TSIZE (1u << 19)
#define TMASK (TSIZE - 1u)
#define HID   32
#define PRIME1 2654435761u
#define PRIME2 805459861u
#define NGROUP 8
#define FSTRIDE 72   // halves per point-row in LDS (16B-aligned: 144 B)

struct Scales { float s[LVL]; };

typedef _Float16 f16x8 __attribute__((ext_vector_type(8)));
typedef float    f32x4 __attribute__((ext_vector_type(4)));

__device__ __forceinline__ float elu_f(float v) {
    return v > 0.0f ? v : expm1f(v);
}
__device__ __forceinline__ _Float16 us_as_h(unsigned short u) {
    _Float16 h; __builtin_memcpy(&h, &u, 2); return h;
}

// ---------------------------------------------------------------------------
// hash encode (unchanged R4 structure): XCD-sharded, fp32 table, fp16 feats out
// ---------------------------------------------------------------------------
__device__ __forceinline__ float2 enc_level_f32(float xn0, float xn1, float xn2, float s,
                                                const float2* __restrict__ tb)
{
    float px = xn0 * s, py = xn1 * s, pz = xn2 * s;
    float fx = floorf(px), fy = floorf(py), fz = floorf(pz);
    float wx = px - fx, wy = py - fy, wz = pz - fz;
    unsigned x0 = (unsigned)fx, y0 = (unsigned)fy, z0 = (unsigned)fz;

    unsigned hy0 = y0 * PRIME1, hy1 = hy0 + PRIME1;
    unsigned hz0 = z0 * PRIME2, hz1 = hz0 + PRIME2;
    unsigned b00 = hy0 ^ hz0, b10 = hy1 ^ hz0, b01 = hy0 ^ hz1, b11 = hy1 ^ hz1;

    float2 g000 = tb[( x0       ^ b00) & TMASK];
    float2 g100 = tb[((x0 + 1u) ^ b00) & TMASK];
    float2 g010 = tb[( x0       ^ b10) & TMASK];
    float2 g110 = tb[((x0 + 1u) ^ b10) & TMASK];
    float2 g001 = tb[( x0       ^ b01) & TMASK];
    float2 g101 = tb[((x0 + 1u) ^ b01) & TMASK];
    float2 g011 = tb[( x0       ^ b11) & TMASK];
    float2 g111 = tb[((x0 + 1u) ^ b11) & TMASK];

    float ux = 1.0f - wx, uy = 1.0f - wy, uz = 1.0f - wz;
    float c00 = uy*uz, c10 = wy*uz, c01 = uy*wz, c11 = wy*wz;

    float f0 = ux * (c00*g000.x + c10*g010.x + c01*g001.x + c11*g011.x)
             + wx * (c00*g100.x + c10*g110.x + c01*g101.x + c11*g111.x);
    float f1 = ux * (c00*g000.y + c10*g010.y + c01*g001.y + c11*g011.y)
             + wx * (c00*g100.y + c10*g110.y + c01*g101.y + c11*g111.y);
    return make_float2(f0, f1);
}

__global__ __launch_bounds__(256, 8)
void hash_kernel(const float* __restrict__ x, const float2* __restrict__ table,
                 ushort4* __restrict__ feats, int n, Scales sc)
{
    int g = blockIdx.x & (NGROUP - 1);
    int p = (blockIdx.x >> 3) * blockDim.x + threadIdx.x;
    if (p >= n) return;

    float xn0 = (x[3*p+0] + 1.0f) * 0.5f;
    float xn1 = (x[3*p+1] + 1.0f) * 0.5f;
    float xn2 = (x[3*p+2] + 1.0f) * 0.5f;

    int l0 = g, l1 = g + NGROUP;
    float2 fa = enc_level_f32(xn0, xn1, xn2, sc.s[l0], table + (size_t)l0 * TSIZE);
    float2 fb = enc_level_f32(xn0, xn1, xn2, sc.s[l1], table + (size_t)l1 * TSIZE);

    ushort4 pk;
    pk.x = __half_as_ushort(__float2half_rn(fa.x));
    pk.y = __half_as_ushort(__float2half_rn(fa.y));
    pk.z = __half_as_ushort(__float2half_rn(fb.x));
    pk.w = __half_as_ushort(__float2half_rn(fb.y));
    feats[(size_t)g * n + p] = pk;
}

// ---------------------------------------------------------------------------
// prep: bake weight B-fragments (hi/lo split f16) in MFMA lane order.
// frag f, lane l, j: B[k = (l>>4)*8+j][n = l&15] of the layer's weight tile.
//  f0..3  L0 hi (kt,nt)=(0,0)(0,1)(1,0)(1,1)   f4..7  L0 lo
//  f8,9   L1 hi nt=0,1                         f10,11 L1 lo
//  f12    L2 hi                                f13    L2 lo
// L0 K-layout (64): k<32 hash feats -> W0 row 3+k ; 32..34 coord_hi -> W0 row k-32;
//                   35..37 coord_lo -> W0 row k-35 (duplicated row!); else 0.
// ---------------------------------------------------------------------------
__global__ void prep_frags(const float* __restrict__ W0, const float* __restrict__ W1,
                           const float* __restrict__ Wout, _Float16* __restrict__ frags)
{
    int idx = blockIdx.x * blockDim.x + threadIdx.x;   // 14*64*8 = 7168
    if (idx >= 14*64*8) return;
    int f = idx >> 9;
    int rem = idx & 511;
    int lane = rem >> 3;
    int j = rem & 7;
    int q = lane >> 4;
    int nn = lane & 15;

    float w = 0.0f;
    bool lo;
    if (f < 8) {
        int part = f >> 2, kt = (f >> 1) & 1, nt = f & 1;
        int k = kt*32 + q*8 + j;
        int ncol = nt*16 + nn;
        float val = 0.0f;
        if (k < 32)      val = W0[(3 + k)  * HID + ncol];
        else if (k < 35) val = W0[(k - 32) * HID + ncol];
        else if (k < 38) val = W0[(k - 35) * HID + ncol];
        w = val; lo = (part == 1);
    } else if (f < 12) {
        int part = (f - 8) >> 1, nt = (f - 8) & 1;
        int k = q*8 + j;
        int ncol = nt*16 + nn;
        w = W1[k * HID + ncol]; lo = (part == 1);
    } else {
        int part = f - 12;
        int k = q*8 + j;
        w = (nn == 0) ? Wout[k] : 0.0f; lo = (part == 1);
    }
    _Float16 hi = (_Float16)w;
    frags[idx] = lo ? (_Float16)(w - (float)hi) : hi;
}

// ---------------------------------------------------------------------------
// MLP via MFMA. Block = 256 pts, 4 waves x 4 M-tiles of 16 pts.
// Split-f16 (hi+lo) weights & activations -> fp32-class accuracy.
// Verified layouts (guide m89/m91/m120): A[m=lane&15][k=(lane>>4)*8+j],
// B[k=(lane>>4)*8+j][n=lane&15], C/D[m=(lane>>4)*4+r][n=lane&15].
// ---------------------------------------------------------------------------
__global__ __launch_bounds__(256, 3)
void mlp_mfma_kernel(const float* __restrict__ x, const ushort4* __restrict__ feats,
                     const float* __restrict__ b0, const float* __restrict__ b1,
                     const float* __restrict__ bout, const _Float16* __restrict__ fragbuf,
                     float* __restrict__ out, int n)
{
    __shared__ __attribute__((aligned(16))) _Float16 featL[256 * FSTRIDE];
    __shared__ __attribute__((aligned(16))) _Float16 h1h[4][16*32], h1l[4][16*32];
    __shared__ __attribute__((aligned(16))) _Float16 h2h[4][16*32], h2l[4][16*32];

    const int t = threadIdx.x;
    const int pbase = blockIdx.x * 256;
    const int p  = pbase + t;
    const int pc = p < n ? p : n - 1;

    // ---- scatter phase: one point per thread -> featL[t][0..63] ----
    {
        _Float16* row = &featL[t * FSTRIDE];
#pragma unroll
        for (int g = 0; g < NGROUP; ++g) {
            ushort4 pk = feats[(size_t)g * n + pc];
            row[2*g + 0]  = us_as_h(pk.x);
            row[2*g + 1]  = us_as_h(pk.y);
            row[16 + 2*g] = us_as_h(pk.z);
            row[17 + 2*g] = us_as_h(pk.w);
        }
        float xn0 = (x[3*pc+0] + 1.0f) * 0.5f;
        float xn1 = (x[3*pc+1] + 1.0f) * 0.5f;
        float xn2 = (x[3*pc+2] + 1.0f) * 0.5f;
        _Float16 h0 = (_Float16)xn0, h1_ = (_Float16)xn1, h2_ = (_Float16)xn2;
        row[32] = h0; row[33] = h1_; row[34] = h2_;
        row[35] = (_Float16)(xn0 - (float)h0);
        row[36] = (_Float16)(xn1 - (float)h1_);
        row[37] = (_Float16)(xn2 - (float)h2_);
#pragma unroll
        for (int k = 38; k < 64; ++k) row[k] = (_Float16)0.0f;
    }
    __syncthreads();

    const int l = t & 63, w = t >> 6;
    const int q = l >> 4, nn = l & 15;

    // ---- loop-invariant: B-fragments (one coalesced 16B load each) + biases ----
    const f16x8* FB = (const f16x8*)fragbuf;
    f16x8 B0h00 = FB[0*64 + l], B0h01 = FB[1*64 + l];
    f16x8 B0h10 = FB[2*64 + l], B0h11 = FB[3*64 + l];
    f16x8 B0l00 = FB[4*64 + l], B0l01 = FB[5*64 + l];
    f16x8 B0l10 = FB[6*64 + l], B0l11 = FB[7*64 + l];
    f16x8 B1h0  = FB[8*64 + l], B1h1  = FB[9*64 + l];
    f16x8 B1l0  = FB[10*64 + l], B1l1 = FB[11*64 + l];
    f16x8 B2h   = FB[12*64 + l], B2l  = FB[13*64 + l];

    float bias00 = b0[nn], bias01 = b0[16 + nn];
    float bias10 = b1[nn], bias11 = b1[16 + nn];
    float biasO  = (nn == 0) ? bout[0] : 0.0f;

    _Float16* H1h = &h1h[w][0]; _Float16* H1l = &h1l[w][0];
    _Float16* H2h = &h2h[w][0]; _Float16* H2l = &h2l[w][0];

#pragma unroll
    for (int mt = 0; mt < 4; ++mt) {
        const int mrow = w*64 + mt*16 + nn;       // this lane's A-row (point) in block
        const _Float16* arow = &featL[mrow * FSTRIDE];

        // ---- layer 0 (A exact; B split hi+lo) ----
        f16x8 A0 = *(const f16x8*)(arow + q*8);        // k-tile 0
        f16x8 A1 = *(const f16x8*)(arow + 32 + q*8);   // k-tile 1
        f32x4 c0 = {bias00, bias00, bias00, bias00};
        f32x4 c1 = {bias01, bias01, bias01, bias01};
        c0 = __builtin_amdgcn_mfma_f32_16x16x32_f16(A0, B0h00, c0, 0, 0, 0);
        c0 = __builtin_amdgcn_mfma_f32_16x16x32_f16(A1, B0h10, c0, 0, 0, 0);
        c0 = __builtin_amdgcn_mfma_f32_16x16x32_f16(A0, B0l00, c0, 0, 0, 0);
        c0 = __builtin_amdgcn_mfma_f32_16x16x32_f16(A1, B0l10, c0, 0, 0, 0);
        c1 = __builtin_amdgcn_mfma_f32_16x16x32_f16(A0, B0h01, c1, 0, 0, 0);
        c1 = __builtin_amdgcn_mfma_f32_16x16x32_f16(A1, B0h11, c1, 0, 0, 0);
        c1 = __builtin_amdgcn_mfma_f32_16x16x32_f16(A0, B0l01, c1, 0, 0, 0);
        c1 = __builtin_amdgcn_mfma_f32_16x16x32_f16(A1, B0l11, c1, 0, 0, 0);

        // ELU -> split -> per-wave LDS tile h1[16][32]
#pragma unroll
        for (int r = 0; r < 4; ++r) {
            int m = q*4 + r;
            float e0 = elu_f(c0[r]);
            _Float16 hh = (_Float16)e0;
            H1h[m*32 + nn]      = hh;
            H1l[m*32 + nn]      = (_Float16)(e0 - (float)hh);
            float e1 = elu_f(c1[r]);
            hh = (_Float16)e1;
            H1h[m*32 + 16 + nn] = hh;
            H1l[m*32 + 16 + nn] = (_Float16)(e1 - (float)hh);
        }

        // ---- layer 1 (A split, B split; drop lo*lo) ----
        f16x8 Ah = *(const f16x8*)(H1h + nn*32 + q*8);
        f16x8 Al = *(const f16x8*)(H1l + nn*32 + q*8);
        f32x4 d0 = {bias10, bias10, bias10, bias10};
        f32x4 d1 = {bias11, bias11, bias11, bias11};
        d0 = __builtin_amdgcn_mfma_f32_16x16x32_f16(Ah, B1h0, d0, 0, 0, 0);
        d0 = __builtin_amdgcn_mfma_f32_16x16x32_f16(Ah, B1l0, d0, 0, 0, 0);
        d0 = __builtin_amdgcn_mfma_f32_16x16x32_f16(Al, B1h0, d0, 0, 0, 0);
        d1 = __builtin_amdgcn_mfma_f32_16x16x32_f16(Ah, B1h1, d1, 0, 0, 0);
        d1 = __builtin_amdgcn_mfma_f32_16x16x32_f16(Ah, B1l1, d1, 0, 0, 0);
        d1 = __builtin_amdgcn_mfma_f32_16x16x32_f16(Al, B1h1, d1, 0, 0, 0);

#pragma unroll
        for (int r = 0; r < 4; ++r) {
            int m = q*4 + r;
            float e0 = elu_f(d0[r]);
            _Float16 hh = (_Float16)e0;
            H2h[m*32 + nn]      = hh;
            H2l[m*32 + nn]      = (_Float16)(e0 - (float)hh);
            float e1 = elu_f(d1[r]);
            hh = (_Float16)e1;
            H2h[m*32 + 16 + nn] = hh;
            H2l[m*32 + 16 + nn] = (_Float16)(e1 - (float)hh);
        }

        // ---- output layer (N=16 padded, col 0 = Wout) ----
        f16x8 A2h = *(const f16x8*)(H2h + nn*32 + q*8);
        f16x8 A2l = *(const f16x8*)(H2l + nn*32 + q*8);
        f32x4 c3 = {biasO, biasO, biasO, biasO};
        c3 = __builtin_amdgcn_mfma_f32_16x16x32_f16(A2h, B2h, c3, 0, 0, 0);
        c3 = __builtin_amdgcn_mfma_f32_16x16x32_f16(A2h, B2l, c3, 0, 0, 0);
        c3 = __builtin_amdgcn_mfma_f32_16x16x32_f16(A2l, B2h, c3, 0, 0, 0);

        if (nn == 0) {
            int pout = pbase + w*64 + mt*16 + q*4;
#pragma unroll
            for (int r = 0; r < 4; ++r)
                if (pout + r < n) out[pout + r] = c3[r];
        }
    }
}

// ---- fallback: fused fp32 one-thread-per-point (known-correct, ~2050 us) ----
__global__ __launch_bounds__(256, 4)
void fused_fp32_kernel(const float* __restrict__ x, const float* __restrict__ table,
                       const float* __restrict__ W0, const float* __restrict__ b0,
                       const float* __restrict__ W1, const float* __restrict__ b1,
                       const float* __restrict__ Wout, const float* __restrict__ bout,
                       float* __restrict__ out, int n, Scales sc)
{
    int tid = blockIdx.x * blockDim.x + threadIdx.x;
    if (tid >= n) return;

    float xn0 = (x[3*tid+0] + 1.0f) * 0.5f;
    float xn1 = (x[3*tid+1] + 1.0f) * 0.5f;
    float xn2 = (x[3*tid+2] + 1.0f) * 0.5f;

    float acc[HID];
#pragma unroll
    for (int j = 0; j < HID; ++j)
        acc[j] = b0[j] + xn0 * W0[0*HID + j] + xn1 * W0[1*HID + j] + xn2 * W0[2*HID + j];

#pragma unroll
    for (int lv = 0; lv < LVL; ++lv) {
        const float2* tb = (const float2*)table + (size_t)lv * TSIZE;
        float2 f = enc_level_f32(xn0, xn1, xn2, sc.s[lv], tb);
        const float* w0r0 = W0 + (3 + 2*lv) * HID;
        const float* w0r1 = W0 + (4 + 2*lv) * HID;
#pragma unroll
        for (int j = 0; j < HID; ++j)
            acc[j] += f.x * w0r0[j] + f.y * w0r1[j];
    }
#pragma unroll
    for (int j = 0; j < HID; ++j) acc[j] = elu_f(acc[j]);

    float acc2[HID];
#pragma unroll
    for (int j = 0; j < HID; ++j) acc2[j] = b1[j];
#pragma unroll
    for (int k = 0; k < HID; ++k) {
        float hk = acc[k];
        const float* w1r = W1 + k * HID;
#pragma unroll
        for (int j = 0; j < HID; ++j) acc2[j] += hk * w1r[j];
    }
    float o = bout[0];
#pragma unroll
    for (int k = 0; k < HID; ++k) o += elu_f(acc2[k]) * Wout[k];
    out[tid] = o;
}

extern "C" void kernel_launch(void* const* d_in, const int* in_sizes, int n_in,
                              void* d_out, int out_size, void* d_ws, size_t ws_size,
                              hipStream_t stream)
{
    const float* x    = (const float*)d_in[0];
    const float* tb   = (const float*)d_in[1];
    const float* W0   = (const float*)d_in[2];
    const float* b0   = (const float*)d_in[3];
    const float* W1   = (const float*)d_in[4];
    const float* b1   = (const float*)d_in[5];
    const float* Wout = (const float*)d_in[6];
    const float* bo   = (const float*)d_in[7];
    float* out = (float*)d_out;

    int n = in_sizes[0] / 3;

    Scales sc;
    double B = exp(log(32.0) / 15.0);
    for (int l = 0; l < LVL; ++l)
        sc.s[l] = (float)(16.0 * pow(B, (double)l) - 1.0);

    const size_t feat_bytes = (size_t)n * NGROUP * sizeof(ushort4);  // 128e6 B @ n=2M
    const size_t frag_bytes = 14 * 64 * 8 * sizeof(_Float16);        // 14336 B
    int block = 256;
    int pgrid = (n + block - 1) / block;

    if (ws_size >= feat_bytes + frag_bytes) {
        ushort4*  feats = (ushort4*)d_ws;
        _Float16* frags = (_Float16*)((char*)d_ws + feat_bytes);
        hash_kernel<<<pgrid * NGROUP, block, 0, stream>>>(x, (const float2*)tb, feats, n, sc);
        prep_frags<<<28, 256, 0, stream>>>(W0, W1, Wout, frags);
        mlp_mfma_kernel<<<pgrid, block, 0, stream>>>(x, feats, b0, b1, bo, frags, out, n);
    } else {
        fused_fp32_kernel<<<pgrid, block, 0, stream>>>(x, tb, W0, b0, W1, b1, Wout, bo, out, n, sc);
    }
}